// Round 5
// baseline (19083.078 us; speedup 1.0000x reference)
//
#include <hip/hip_runtime.h>
#include <math.h>

#define BDIM 256
#define DDIM 2048
constexpr float DT    = 0.1f;
constexpr float TOL   = 0.01f;
constexpr int   NSTEP = 50;      // int(5.0 / 0.1)
constexpr float EPS_  = 1e-8f;

typedef __attribute__((ext_vector_type(8))) short short8;   // 8 bf16 (MFMA A/B frag)
typedef __attribute__((ext_vector_type(4))) float f32x4;    // MFMA C/D frag

__device__ __forceinline__ ushort f2bf(float f) {           // fp32 -> bf16 RNE
    unsigned u = __float_as_uint(f);
    return (ushort)((u + 0x7fffu + ((u >> 16) & 1u)) >> 16);
}
__device__ __forceinline__ float bf2f(ushort h) { return __uint_as_float(((unsigned)h) << 16); }

#define GLOAD_LDS16(g, l) __builtin_amdgcn_global_load_lds( \
    (const __attribute__((address_space(1))) void*)(g),      \
    (__attribute__((address_space(3))) void*)(l), 16, 0, 0)

#define MFMA16(a, b, c) __builtin_amdgcn_mfma_f32_16x16x32_bf16((a), (b), (c), 0, 0, 0)

// ---------------------------------------------------------------------------
// One-time prepack: W -> bf16 hi/lo row-major (NT B operand: W[n][k] k-contig)
// ---------------------------------------------------------------------------
__global__ __launch_bounds__(256)
void prep_w_k(const float* __restrict__ W, ushort* __restrict__ Wh, ushort* __restrict__ Wl)
{
    const size_t i = ((size_t)blockIdx.x * 256 + threadIdx.x) * 4;
    const float4 v = *(const float4*)(W + i);
    ushort4 h, l;
    h.x = f2bf(v.x); l.x = f2bf(v.x - bf2f(h.x));
    h.y = f2bf(v.y); l.y = f2bf(v.y - bf2f(h.y));
    h.z = f2bf(v.z); l.z = f2bf(v.z - bf2f(h.z));
    h.w = f2bf(v.w); l.w = f2bf(v.w - bf2f(h.w));
    *(ushort4*)(Wh + i) = h;
    *(ushort4*)(Wl + i) = l;
}

// One-time prepack: W^T -> bf16 hi/lo (NN B operand: Wt[n][k]=W[k][n] k-contig)
__global__ __launch_bounds__(256)
void prep_wt_k(const float* __restrict__ W, ushort* __restrict__ Wth, ushort* __restrict__ Wtl)
{
    __shared__ float T[64][65];
    const int t = threadIdx.x;
    const int k0 = blockIdx.y * 64, n0 = blockIdx.x * 64;
    const int r = t >> 2, c4 = (t & 3) * 16;
    const float* src = W + (size_t)(k0 + r) * DDIM + n0 + c4;
    #pragma unroll
    for (int j = 0; j < 4; ++j) {
        const float4 v = *(const float4*)(src + j * 4);
        T[r][c4 + j*4 + 0] = v.x; T[r][c4 + j*4 + 1] = v.y;
        T[r][c4 + j*4 + 2] = v.z; T[r][c4 + j*4 + 3] = v.w;
    }
    __syncthreads();
    ushort hb[16], lb[16];
    #pragma unroll
    for (int j = 0; j < 16; ++j) {
        const float v = T[c4 + j][r];
        hb[j] = f2bf(v); lb[j] = f2bf(v - bf2f(hb[j]));
    }
    ushort* oh = Wth + (size_t)(n0 + r) * DDIM + k0 + c4;
    ushort* ol = Wtl + (size_t)(n0 + r) * DDIM + k0 + c4;
    #pragma unroll
    for (int q = 0; q < 4; ++q) {
        *(ushort4*)(oh + q*4) = make_ushort4(hb[q*4], hb[q*4+1], hb[q*4+2], hb[q*4+3]);
        *(ushort4*)(ol + q*4) = make_ushort4(lb[q*4], lb[q*4+1], lb[q*4+2], lb[q*4+3]);
    }
}

// init: x = x0; As = split(x0); zero csum/maxu/done
__global__ __launch_bounds__(256)
void init3_k(const float* __restrict__ x0, float* __restrict__ x,
             ushort* __restrict__ Ash, ushort* __restrict__ Asl,
             float* __restrict__ csum, unsigned* __restrict__ maxu, int* __restrict__ done)
{
    const size_t i = ((size_t)blockIdx.x * 256 + threadIdx.x) * 4;
    const float4 v = *(const float4*)(x0 + i);
    *(float4*)(x + i) = v;
    ushort4 h, l;
    h.x = f2bf(v.x); l.x = f2bf(v.x - bf2f(h.x));
    h.y = f2bf(v.y); l.y = f2bf(v.y - bf2f(h.y));
    h.z = f2bf(v.z); l.z = f2bf(v.z - bf2f(h.z));
    h.w = f2bf(v.w); l.w = f2bf(v.w - bf2f(h.w));
    *(ushort4*)(Ash + i) = h;
    *(ushort4*)(Asl + i) = l;
    if (blockIdx.x == 0) {
        for (int j = threadIdx.x; j < 1024; j += 256) csum[j] = 0.f;
        if (threadIdx.x == 0) { *maxu = 0u; *done = 0; }
    }
}

// ---------------------------------------------------------------------------
// Split-bf16 MFMA GEMM v5. Tile 32x32, BK=64, 256 thr (4 waves = 2x2 of
// 16x16), grid (64,8)=512 -> 2 blocks/CU.
//  * A-frags: DIRECT global->VGPR loads (no LDS), 64B-coalesced, L1/L2-hot.
//  * B: LDS-staged via global_load_lds, 3 buffers, 2-deep prefetch.
//    A-loads issued BEFORE stage(it+2): the compiler's vmcnt wait for the A
//    frags (vmcnt(2)) retires stage(it+1) by FIFO order -> no vmcnt(0) drain
//    anywhere in the loop. Raw s_barrier (not __syncthreads) once per K-step.
//  * XOR-swizzled B tiles (pre-swizzled DMA source + swizzled ds_read).
//  * Dual accumulator chains (ks=0 / ks=1) break MFMA dependency stalls.
// MODE 0: NN  z=A@Wt; epi: h=tanh(z+b), store P=split(h(1-h^2)), csum+=h^2
// MODE 1: NT  kv=-cf*(P@W^T); epi: S=kv, max|kv|, As=split(x+0.5DT*kv)
// MODE 2: NT  epi: S+=2kv, As=split(x+0.5DT*kv)
// MODE 3: NT  epi: S+=2kv, As=split(x+DT*kv)
// MODE 4: NT  epi: x+=DT/6*(S+kv), As=split(x_new)
// NT modes zero cs_next (block 0,0) at kernel end.
// ---------------------------------------------------------------------------
template<int MODE>
__global__ __launch_bounds__(256, 2)
void hop5_mm(const ushort* __restrict__ Ahg, const ushort* __restrict__ Alg,
             const ushort* __restrict__ Bhg, const ushort* __restrict__ Blg,
             const float* __restrict__ bias,
             ushort* __restrict__ Oh, ushort* __restrict__ Ol,
             float* __restrict__ cs_cur, float* __restrict__ cs_next,
             const float* __restrict__ xin, float* __restrict__ xio,
             float* __restrict__ S,
             ushort* __restrict__ Ash, ushort* __restrict__ Asl,
             float cmul, unsigned* __restrict__ maxu, const int* __restrict__ done)
{
    constexpr bool NN = (MODE == 0);
    if (*done) return;

    // 3 x [species(2)][32 rows][64 shorts] = 24 KB (B only)
    __shared__ __align__(16) ushort lds[3][4096];

    const int t = threadIdx.x, lane = t & 63, wid = t >> 6;
    const int wr = wid >> 1, wc = wid & 1;
    const int row0 = blockIdx.y * 32, col0 = blockIdx.x * 32;
    const int fr = lane & 15, kq = (lane >> 4) * 8;

    // ---- A-frag global base (element offset); lane reads 16B of one row ----
    const size_t aoff = (size_t)(row0 + wr * 16 + fr) * DDIM + kq;
    const ushort* aH = Ahg + aoff;
    const ushort* aL = Alg + aoff;

    // ---- B staging: wave wid stages rows wid*8..+7, both species ----
    const int srow = lane >> 3;                               // 0..7
    const int bs_k = ((lane & 7) * 8) ^ ((srow & 7) << 3);    // pre-swizzled source
    const ushort* bs_h = Bhg + (size_t)(col0 + wid * 8 + srow) * DDIM + bs_k;
    const ushort* bs_l = Blg + (size_t)(col0 + wid * 8 + srow) * DDIM + bs_k;
    auto stageB = [&](int it, int b) {
        GLOAD_LDS16(bs_h + it * 64, &lds[b][wid * 512]);
        GLOAD_LDS16(bs_l + it * 64, &lds[b][2048 + wid * 512]);
    };

    // ---- B frag read coords (swizzled) ----
    const int brow = wc * 16 + fr;
    const int sb = (brow & 7) << 3;
    const int kb0 = kq ^ sb, kb1 = (32 + kq) ^ sb;
    const int boff0 = brow * 64 + kb0, boff1 = brow * 64 + kb1;

    f32x4 acc_e = {0.f, 0.f, 0.f, 0.f};
    f32x4 acc_o = {0.f, 0.f, 0.f, 0.f};

    stageB(0, 0); stageB(1, 1);
    asm volatile("s_waitcnt vmcnt(2)" ::: "memory");   // buf0 ready; buf1 in flight
    __builtin_amdgcn_sched_barrier(0);
    __builtin_amdgcn_s_barrier();
    __builtin_amdgcn_sched_barrier(0);

    int b = 0;       // buffer holding tile `it`
    for (int it = 0; it < 32; ++it) {
        // A loads FIRST (their vmcnt wait retires stage(it+1), not stage(it+2))
        const short8 ah0 = *(const short8*)(aH + it * 64);
        const short8 ah1 = *(const short8*)(aH + it * 64 + 32);
        const short8 al0 = *(const short8*)(aL + it * 64);
        const short8 al1 = *(const short8*)(aL + it * 64 + 32);
        asm volatile("" ::: "memory");                 // keep A-loads before DMA
        if (it < 30) {
            int nb = b + 2; if (nb >= 3) nb -= 3;
            stageB(it + 2, nb);
        }
        __builtin_amdgcn_sched_barrier(0);

        const ushort* buf = &lds[b][0];
        const short8 bh0 = *(const short8*)&buf[boff0];
        const short8 bl0 = *(const short8*)&buf[2048 + boff0];
        const short8 bh1 = *(const short8*)&buf[boff1];
        const short8 bl1 = *(const short8*)&buf[2048 + boff1];

        acc_e = MFMA16(ah0, bh0, acc_e);
        acc_o = MFMA16(ah1, bh1, acc_o);
        acc_e = MFMA16(ah0, bl0, acc_e);
        acc_o = MFMA16(ah1, bl1, acc_o);
        acc_e = MFMA16(al0, bh0, acc_e);
        acc_o = MFMA16(al1, bh1, acc_o);

        __builtin_amdgcn_sched_barrier(0);
        __builtin_amdgcn_s_barrier();
        __builtin_amdgcn_sched_barrier(0);
        ++b; if (b == 3) b = 0;
    }

    f32x4 acc;
    #pragma unroll
    for (int j = 0; j < 4; ++j) acc[j] = acc_e[j] + acc_o[j];

    // ---- epilogue. C/D: col=lane&15, row=(lane>>4)*4+j ----
    const int r0 = row0 + wr * 16 + (lane >> 4) * 4;
    const int c0 = col0 + wc * 16 + fr;

    if constexpr (NN) {
        const float b0 = bias[c0];
        float s2[4];
        #pragma unroll
        for (int j = 0; j < 4; ++j) {
            const float h0 = tanhf(acc[j] + b0);
            s2[j] = h0 * h0;
            const float p0 = h0 * (1.f - h0 * h0);
            const size_t i0 = (size_t)(r0 + j) * DDIM + c0;
            const ushort ph = f2bf(p0);
            Oh[i0] = ph; Ol[i0] = f2bf(p0 - bf2f(ph));
        }
        #pragma unroll
        for (int m = 1; m <= 8; m <<= 1)
            #pragma unroll
            for (int j = 0; j < 4; ++j) s2[j] += __shfl_xor(s2[j], m);
        if (fr == 0) {
            #pragma unroll
            for (int j = 0; j < 4; ++j) atomicAdd(&cs_cur[r0 + j], s2[j]);
        }
    } else {
        float mx = 0.f;
        #pragma unroll
        for (int j = 0; j < 4; ++j) {
            const float cf = 5.0f / (sqrtf(cs_cur[r0 + j]) + EPS_);
            const float kv = -cf * acc[j];
            const size_t idx = (size_t)(r0 + j) * DDIM + c0;
            if constexpr (MODE == 1) { S[idx] = kv; mx = fmaxf(mx, fabsf(kv)); }
            if constexpr (MODE == 2 || MODE == 3) { S[idx] += 2.f * kv; }
            if constexpr (MODE <= 3) {
                const float a = xin[idx] + cmul * kv;
                const ushort ah = f2bf(a);
                Ash[idx] = ah; Asl[idx] = f2bf(a - bf2f(ah));
            } else {
                const float xn = xin[idx] + (DT / 6.0f) * (S[idx] + kv);
                xio[idx] = xn;
                const ushort ah = f2bf(xn);
                Ash[idx] = ah; Asl[idx] = f2bf(xn - bf2f(ah));
            }
        }
        if constexpr (MODE == 1) {
            #pragma unroll
            for (int m = 1; m <= 32; m <<= 1) mx = fmaxf(mx, __shfl_xor(mx, m));
            if (lane == 0) atomicMax(maxu, __float_as_uint(mx));
        }
    }

    if (!NN && blockIdx.x == 0 && blockIdx.y == 0) cs_next[t] = 0.f;
}

__global__ void finalize_k(unsigned* __restrict__ maxu, int* __restrict__ done)
{
    if (!*done) {
        if (__uint_as_float(*maxu) < TOL) *done = 1;
    }
    *maxu = 0u;
}

__global__ __launch_bounds__(256)
void copy_k(const float* __restrict__ src, float* __restrict__ dst)
{
    const size_t i = ((size_t)blockIdx.x * 256 + threadIdx.x) * 4;
    *(float4*)&dst[i] = *(const float4*)&src[i];
}

// ===========================================================================
extern "C" void kernel_launch(void* const* d_in, const int* in_sizes, int n_in,
                              void* d_out, int out_size, void* d_ws, size_t ws_size,
                              hipStream_t stream)
{
    const float* x0   = (const float*)d_in[0];
    const float* W    = (const float*)d_in[1];
    const float* bias = (const float*)d_in[2];
    float* out = (float*)d_out;

    const size_t NE = (size_t)BDIM * DDIM;   // 524288
    const size_t M4 = (size_t)DDIM * DDIM;   // 4194304

    // ws layout (~42 MB; r2-r4 proved ws_size >= 44 MB by running this path)
    float* ws = (float*)d_ws;
    float* x    = ws;                        // NE
    float* S    = ws + NE;                   // NE
    float* csum = ws + 2 * NE;               // 1024 (4 stage buffers x 256)
    unsigned* maxu = (unsigned*)(csum + 1024);
    int*      done = (int*)(maxu + 1);
    ushort* us = (ushort*)(ws + 2 * NE + 1032);   // 16B-aligned
    ushort* Ash = us;                // NE: A-side (x + c*k) hi
    ushort* Asl = us + NE;           // NE
    ushort* Ph  = us + 2 * NE;       // NE: p = h(1-h^2) hi
    ushort* Pl  = us + 3 * NE;       // NE
    ushort* Wth = us + 4 * NE;       // M4: W^T hi (NN B)
    ushort* Wtl = Wth + M4;          // M4
    ushort* Wh  = Wth + 2 * M4;      // M4: W hi (NT B)
    ushort* Wl  = Wth + 3 * M4;      // M4

    prep_w_k <<<4096, 256, 0, stream>>>(W, Wh, Wl);
    prep_wt_k<<<dim3(32, 32), 256, 0, stream>>>(W, Wth, Wtl);
    init3_k  <<<512, 256, 0, stream>>>(x0, x, Ash, Asl, csum, maxu, done);

    const dim3 gG(DDIM / 32, BDIM / 32);     // (64, 8) = 512 blocks, 2/CU
    float* cs0 = csum, *cs1 = csum + 256, *cs2 = csum + 512, *cs3 = csum + 768;

    for (int s = 0; s < NSTEP; ++s) {
        // k1 = pvf(x): NN then NT(mode1) + stop condition
        hop5_mm<0><<<gG, 256, 0, stream>>>(Ash, Asl, Wth, Wtl, bias, Ph, Pl,
                                           cs0, nullptr, nullptr, nullptr, nullptr,
                                           nullptr, nullptr, 0.f, nullptr, done);
        hop5_mm<1><<<gG, 256, 0, stream>>>(Ph, Pl, Wh, Wl, nullptr, nullptr, nullptr,
                                           cs0, cs1, x, nullptr, S,
                                           Ash, Asl, 0.5f * DT, maxu, done);
        finalize_k<<<1, 1, 0, stream>>>(maxu, done);
        // k2
        hop5_mm<0><<<gG, 256, 0, stream>>>(Ash, Asl, Wth, Wtl, bias, Ph, Pl,
                                           cs1, nullptr, nullptr, nullptr, nullptr,
                                           nullptr, nullptr, 0.f, nullptr, done);
        hop5_mm<2><<<gG, 256, 0, stream>>>(Ph, Pl, Wh, Wl, nullptr, nullptr, nullptr,
                                           cs1, cs2, x, nullptr, S,
                                           Ash, Asl, 0.5f * DT, nullptr, done);
        // k3
        hop5_mm<0><<<gG, 256, 0, stream>>>(Ash, Asl, Wth, Wtl, bias, Ph, Pl,
                                           cs2, nullptr, nullptr, nullptr, nullptr,
                                           nullptr, nullptr, 0.f, nullptr, done);
        hop5_mm<3><<<gG, 256, 0, stream>>>(Ph, Pl, Wh, Wl, nullptr, nullptr, nullptr,
                                           cs2, cs3, x, nullptr, S,
                                           Ash, Asl, DT, nullptr, done);
        // k4 + RK4 x-update fused
        hop5_mm<0><<<gG, 256, 0, stream>>>(Ash, Asl, Wth, Wtl, bias, Ph, Pl,
                                           cs3, nullptr, nullptr, nullptr, nullptr,
                                           nullptr, nullptr, 0.f, nullptr, done);
        hop5_mm<4><<<gG, 256, 0, stream>>>(Ph, Pl, Wh, Wl, nullptr, nullptr, nullptr,
                                           cs3, cs0, x, x, S,
                                           Ash, Asl, 0.f, nullptr, done);
    }

    copy_k<<<512, 256, 0, stream>>>(x, out);
}